// Round 1
// baseline (74.936 us; speedup 1.0000x reference)
//
#include <hip/hip_runtime.h>

// Least_Squares_weight: batched weighted 2-D Kabsch with GLOBAL weight sum.
// B=65536 batches, NUM=256 points. Closed-form 2x2 "SVD":
//   R = argmax_{R in SO(2)} tr(R H),  (c,s) ~ (H00+H11, H01-H10)
//   theta = arccos(c)*sign(s) = atan2(H01-H10, H00+H11)
// H = M - saw2 (x) G_B - G_A (x) sbw2 + s2 * G_A (x) G_B
// with per-batch sums: s1=Σw, s2=Σw², sa=Σw·a, sb=Σw·b,
//                      saw2=Σw²·a, sbw2=Σw²·b, M=Σw²·a b^T   (14 scalars)
// G_A = sa/ws, G_B = sb/ws with ws = GLOBAL Σw.

#define NUMPTS 256

// ---------------- kernel 1: per-batch partial sums (one wave per batch) ---
__global__ __launch_bounds__(256) void k_partials(
    const float* __restrict__ A, const float* __restrict__ Bp,
    const float* __restrict__ W, float* __restrict__ P, int Bn)
{
    const int lane = threadIdx.x & 63;
    const int wave = threadIdx.x >> 6;
    const int b = blockIdx.x * 4 + wave;
    if (b >= Bn) return;

    const size_t pb = (size_t)b * (NUMPTS * 2);
    const size_t wb = (size_t)b * NUMPTS;

    const float4* A4 = (const float4*)(A + pb);
    const float4* B4 = (const float4*)(Bp + pb);
    const float4* W4 = (const float4*)(W + wb);

    // lane handles points 4*lane .. 4*lane+3 : 2x float4 from A/B, 1 from W
    float4 a0 = A4[2 * lane], a1 = A4[2 * lane + 1];
    float4 b0 = B4[2 * lane], b1 = B4[2 * lane + 1];
    float4 w4 = W4[lane];

    float s1 = 0.f, s2 = 0.f, sax = 0.f, say = 0.f, sbx = 0.f, sby = 0.f;
    float tax = 0.f, tay = 0.f, tbx = 0.f, tby = 0.f;
    float m00 = 0.f, m01 = 0.f, m10 = 0.f, m11 = 0.f;

#define ACC(ax, ay, bx, by, w) do {                         \
        float _w = (w), _w2 = _w * _w;                      \
        s1 += _w;  s2 += _w2;                               \
        sax += _w * (ax);  say += _w * (ay);                \
        sbx += _w * (bx);  sby += _w * (by);                \
        float _wax = _w2 * (ax), _way = _w2 * (ay);         \
        tax += _wax;  tay += _way;                          \
        tbx += _w2 * (bx);  tby += _w2 * (by);              \
        m00 += _wax * (bx);  m01 += _wax * (by);            \
        m10 += _way * (bx);  m11 += _way * (by);            \
    } while (0)

    ACC(a0.x, a0.y, b0.x, b0.y, w4.x);
    ACC(a0.z, a0.w, b0.z, b0.w, w4.y);
    ACC(a1.x, a1.y, b1.x, b1.y, w4.z);
    ACC(a1.z, a1.w, b1.z, b1.w, w4.w);
#undef ACC

    // 64-lane butterfly reduction of the 14 accumulators
#pragma unroll
    for (int m = 32; m >= 1; m >>= 1) {
        s1  += __shfl_xor(s1, m);   s2  += __shfl_xor(s2, m);
        sax += __shfl_xor(sax, m);  say += __shfl_xor(say, m);
        sbx += __shfl_xor(sbx, m);  sby += __shfl_xor(sby, m);
        tax += __shfl_xor(tax, m);  tay += __shfl_xor(tay, m);
        tbx += __shfl_xor(tbx, m);  tby += __shfl_xor(tby, m);
        m00 += __shfl_xor(m00, m);  m01 += __shfl_xor(m01, m);
        m10 += __shfl_xor(m10, m);  m11 += __shfl_xor(m11, m);
    }

    if (lane == 0) {
        const size_t Bs = (size_t)Bn;
        P[ 0 * Bs + b] = s1;   P[ 1 * Bs + b] = s2;
        P[ 2 * Bs + b] = sax;  P[ 3 * Bs + b] = say;
        P[ 4 * Bs + b] = sbx;  P[ 5 * Bs + b] = sby;
        P[ 6 * Bs + b] = tax;  P[ 7 * Bs + b] = tay;
        P[ 8 * Bs + b] = tbx;  P[ 9 * Bs + b] = tby;
        P[10 * Bs + b] = m00;  P[11 * Bs + b] = m01;
        P[12 * Bs + b] = m10;  P[13 * Bs + b] = m11;
    }
}

// ---------------- kernel 2: deterministic global ws = Σ_b s1[b] ----------
__global__ __launch_bounds__(1024) void k_ws(
    const float* __restrict__ P, float* __restrict__ wsum, int Bn)
{
    const float4* P4 = (const float4*)P;  // s1 array is P[0 .. Bn)
    float acc = 0.f;
    const int n4 = Bn / 4;
    for (int i = threadIdx.x; i < n4; i += 1024) {
        float4 v = P4[i];
        acc += (v.x + v.y) + (v.z + v.w);
    }
#pragma unroll
    for (int m = 32; m >= 1; m >>= 1) acc += __shfl_xor(acc, m);

    __shared__ float sm[16];
    if ((threadIdx.x & 63) == 0) sm[threadIdx.x >> 6] = acc;
    __syncthreads();
    if (threadIdx.x == 0) {
        float v = 0.f;
#pragma unroll
        for (int i = 0; i < 16; ++i) v += sm[i];
        wsum[0] = v;
    }
}

// ---------------- kernel 3: per-batch closed-form solve -------------------
__global__ __launch_bounds__(256) void k_final(
    const float* __restrict__ P, const float* __restrict__ wsum,
    float* __restrict__ out, int Bn)
{
    const int b = blockIdx.x * 256 + threadIdx.x;
    if (b >= Bn) return;
    const size_t Bs = (size_t)Bn;

    const float inv = 1.0f / wsum[0];

    const float s2  = P[ 1 * Bs + b];
    const float sax = P[ 2 * Bs + b], say = P[ 3 * Bs + b];
    const float sbx = P[ 4 * Bs + b], sby = P[ 5 * Bs + b];
    const float tax = P[ 6 * Bs + b], tay = P[ 7 * Bs + b];
    const float tbx = P[ 8 * Bs + b], tby = P[ 9 * Bs + b];
    const float m00 = P[10 * Bs + b], m01 = P[11 * Bs + b];
    const float m10 = P[12 * Bs + b], m11 = P[13 * Bs + b];

    const float GAx = sax * inv, GAy = say * inv;
    const float GBx = sbx * inv, GBy = sby * inv;

    const float H00 = m00 - tax * GBx - GAx * tbx + s2 * GAx * GBx;
    const float H01 = m01 - tax * GBy - GAx * tby + s2 * GAx * GBy;
    const float H10 = m10 - tay * GBx - GAy * tbx + s2 * GAy * GBx;
    const float H11 = m11 - tay * GBy - GAy * tby + s2 * GAy * GBy;

    const float cp = H00 + H11;          // ~ r*cos(theta)
    const float sp = H01 - H10;          // ~ r*sin(theta)
    const float theta = atan2f(sp, cp);  // == arccos(c)*sign(s) of the reference

    const float r = sqrtf(cp * cp + sp * sp);
    const float c = cp / r, s = sp / r;  // R = [[c,-s],[s,c]]

    const float tx = GBx - (c * GAx - s * GAy);
    const float ty = GBy - (s * GAx + c * GAy);

    out[0 * Bs + b] = theta;
    out[1 * Bs + b] = tx;
    out[2 * Bs + b] = ty;
}

// ---------------- launch ---------------------------------------------------
extern "C" void kernel_launch(void* const* d_in, const int* in_sizes, int n_in,
                              void* d_out, int out_size, void* d_ws, size_t ws_size,
                              hipStream_t stream) {
    const float* A  = (const float*)d_in[0];   // pstA  [B,256,2]
    const float* Bp = (const float*)d_in[1];   // pstB  [B,256,2]
    const float* W  = (const float*)d_in[2];   // weight[B,256,1]
    const int Bn = in_sizes[2] / NUMPTS;       // 65536

    float* P    = (float*)d_ws;                // 14 SoA arrays of Bn floats
    float* wsum = P + 14 * (size_t)Bn;         // +1 scalar
    float* out  = (float*)d_out;               // theta[Bn], tx[Bn], ty[Bn]

    hipLaunchKernelGGL(k_partials, dim3(Bn / 4), dim3(256), 0, stream,
                       A, Bp, W, P, Bn);
    hipLaunchKernelGGL(k_ws, dim3(1), dim3(1024), 0, stream, P, wsum, Bn);
    hipLaunchKernelGGL(k_final, dim3(Bn / 256), dim3(256), 0, stream,
                       P, wsum, out, Bn);
}